// Round 1
// baseline (424.793 us; speedup 1.0000x reference)
//
#include <hip/hip_runtime.h>

typedef __attribute__((ext_vector_type(8))) short short8;
typedef __attribute__((ext_vector_type(4))) float floatx4;

#define B_ 8
#define T_ 1024
#define S_ 1500
#define SP 1536
#define D_ 1024
#define H_ 16
#define DH 64
#define SCALE_ 0.125f

__device__ __forceinline__ unsigned short f2bf(float f) {
  unsigned u = __float_as_uint(f);
  u += 0x7fffu + ((u >> 16) & 1u);
  return (unsigned short)(u >> 16);
}

__device__ __forceinline__ floatx4 mfma16(short8 a, short8 b, floatx4 c) {
  return __builtin_amdgcn_mfma_f32_16x16x32_bf16(a, b, c, 0, 0, 0);
}

// ---------------- prep: fp32 -> bf16 cast (vectorized) ----------------
__global__ void cast_bf16_kernel(const float* __restrict__ src,
                                 unsigned short* __restrict__ dst, int n4) {
  int i = blockIdx.x * blockDim.x + threadIdx.x;
  if (i < n4) {
    float4 v = ((const float4*)src)[i];
    ushort4 o;
    o.x = f2bf(v.x); o.y = f2bf(v.y); o.z = f2bf(v.z); o.w = f2bf(v.w);
    ((ushort4*)dst)[i] = o;
  }
}

// ---------------- prep: K [B,S,H,DH] f32 -> [B,H,SP,DH] bf16 (zero-pad s>=S_) ----
__global__ void pack_k_kernel(const float* __restrict__ k,
                              unsigned short* __restrict__ kb) {
  int i = blockIdx.x * blockDim.x + threadIdx.x;  // group of 4 dh
  int dh4 = (i & 15) * 4;
  int j = i >> 4;
  int s = j % SP;
  int bh = j / SP;
  if (bh >= B_ * H_) return;
  int b = bh >> 4, h = bh & 15;
  ushort4 o;
  if (s < S_) {
    float4 v = *(const float4*)(k + (((size_t)(b * S_ + s) * H_ + h) * DH) + dh4);
    o.x = f2bf(v.x); o.y = f2bf(v.y); o.z = f2bf(v.z); o.w = f2bf(v.w);
  } else {
    o = make_ushort4(0, 0, 0, 0);
  }
  *(ushort4*)(kb + ((size_t)bh * SP + s) * DH + dh4) = o;
}

// ---------------- prep: V [B,S,H,DH] f32 -> transposed [B,H,DH,SP] bf16 ----------
__global__ void pack_vt_kernel(const float* __restrict__ v,
                               unsigned short* __restrict__ vt) {
  __shared__ unsigned short tile[64][72];  // [dh][s], padded
  int st = blockIdx.x, bh = blockIdx.y;
  int b = bh >> 4, h = bh & 15;
  int s0 = st * 64;
  int t = threadIdx.x;
  for (int i = t; i < 1024; i += 256) {
    int sl = i >> 4, dh4 = (i & 15) * 4;
    float4 val = make_float4(0.f, 0.f, 0.f, 0.f);
    if (s0 + sl < S_)
      val = *(const float4*)(v + ((size_t)((b * S_ + s0 + sl) * H_ + h)) * DH + dh4);
    tile[dh4 + 0][sl] = f2bf(val.x);
    tile[dh4 + 1][sl] = f2bf(val.y);
    tile[dh4 + 2][sl] = f2bf(val.z);
    tile[dh4 + 3][sl] = f2bf(val.w);
  }
  __syncthreads();
  for (int i = t; i < 1024; i += 256) {
    int d = i >> 4, s4 = (i & 15) * 4;
    ushort4 o;
    o.x = tile[d][s4]; o.y = tile[d][s4 + 1]; o.z = tile[d][s4 + 2]; o.w = tile[d][s4 + 3];
    *(ushort4*)(vt + ((size_t)bh * DH + d) * SP + s0 + s4) = o;
  }
}

// ---------------- bf16 GEMM  C[m,n] = sum_k A[m,k]*B[n,k]  (+bias epilogues) -----
// epi=0: qs output bf16, (val+bias)*SCALE, permuted to [B,H,T,DH]
// epi=1: fp32 output, val+bias, row-major [M,1024]
#define BK 32
#define ASTR 40  // padded LDS stride (shorts)
__global__ __launch_bounds__(256) void gemm_bt(const unsigned short* __restrict__ A,
                                               const unsigned short* __restrict__ Bm,
                                               const float* __restrict__ bias,
                                               void* __restrict__ outp, int epi) {
  __shared__ unsigned short As[128 * ASTR];
  __shared__ unsigned short Bs[128 * ASTR];
  const int K = 1024;
  int t = threadIdx.x;
  int m0 = blockIdx.y * 128, n0 = blockIdx.x * 128;
  int w = t >> 6, lane = t & 63, quad = lane >> 4, l16 = lane & 15;
  int mw = (w & 1) * 64, nw = (w >> 1) * 64;
  int lrow = t >> 2, lcol = (t & 3) * 8;

  const unsigned short* Ag = A + (size_t)(m0 + lrow) * K + lcol;
  const unsigned short* Bg = Bm + (size_t)(n0 + lrow) * K + lcol;

  floatx4 acc[4][4];
#pragma unroll
  for (int i = 0; i < 4; i++)
#pragma unroll
    for (int j = 0; j < 4; j++) {
      floatx4 z = {0.f, 0.f, 0.f, 0.f};
      acc[i][j] = z;
    }

  int4 a0 = *(const int4*)(Ag);
  int4 a1 = *(const int4*)(Ag + (size_t)64 * K);
  int4 b0 = *(const int4*)(Bg);
  int4 b1 = *(const int4*)(Bg + (size_t)64 * K);

  for (int kt = 0; kt < K / BK; kt++) {
    __syncthreads();
    *(int4*)&As[lrow * ASTR + lcol] = a0;
    *(int4*)&As[(lrow + 64) * ASTR + lcol] = a1;
    *(int4*)&Bs[lrow * ASTR + lcol] = b0;
    *(int4*)&Bs[(lrow + 64) * ASTR + lcol] = b1;
    __syncthreads();
    if (kt + 1 < K / BK) {
      a0 = *(const int4*)(Ag + (kt + 1) * BK);
      a1 = *(const int4*)(Ag + (size_t)64 * K + (kt + 1) * BK);
      b0 = *(const int4*)(Bg + (kt + 1) * BK);
      b1 = *(const int4*)(Bg + (size_t)64 * K + (kt + 1) * BK);
    }
    short8 af[4], bf[4];
#pragma unroll
    for (int mi = 0; mi < 4; mi++)
      af[mi] = *(const short8*)&As[(mw + mi * 16 + l16) * ASTR + quad * 8];
#pragma unroll
    for (int ni = 0; ni < 4; ni++)
      bf[ni] = *(const short8*)&Bs[(nw + ni * 16 + l16) * ASTR + quad * 8];
#pragma unroll
    for (int mi = 0; mi < 4; mi++)
#pragma unroll
      for (int ni = 0; ni < 4; ni++)
        acc[mi][ni] = mfma16(af[mi], bf[ni], acc[mi][ni]);
  }

#pragma unroll
  for (int mi = 0; mi < 4; mi++)
#pragma unroll
    for (int ni = 0; ni < 4; ni++) {
      int row = m0 + mw + mi * 16 + quad * 4;
      int col = n0 + nw + ni * 16 + l16;
      float bcol = bias[col];
#pragma unroll
      for (int r = 0; r < 4; r++) {
        float val = acc[mi][ni][r] + bcol;
        int rr = row + r;
        if (epi == 0) {
          int b = rr >> 10, tt = rr & 1023, h = col >> 6, dh = col & 63;
          ((unsigned short*)outp)[(((size_t)(b * 16 + h) * 1024) + tt) * 64 + dh] =
              f2bf(val * SCALE_);
        } else {
          ((float*)outp)[(size_t)rr * 1024 + col] = val;
        }
      }
    }
}

// ---------------- fused flash attention -------------------------------------
// grid (T/64, B*H), block 256 (4 waves); each wave owns 16 Q rows.
__global__ __launch_bounds__(256) void attn_kernel(const unsigned short* __restrict__ qs,
                                                   const unsigned short* __restrict__ kb,
                                                   const unsigned short* __restrict__ vt,
                                                   unsigned short* __restrict__ ob) {
  __shared__ unsigned short Ks[128 * 72];   // [s][d] padded
  __shared__ unsigned short Vs[64 * 136];   // [d][s] padded
  __shared__ unsigned short Ps[64 * 136];   // [t][s] padded
  int ttile = blockIdx.x, bh = blockIdx.y;
  int b = bh >> 4, h = bh & 15;
  int t = threadIdx.x, w = t >> 6, lane = t & 63, quad = lane >> 4, l16 = lane & 15;

  const unsigned short* qp =
      qs + ((size_t)bh * T_ + ttile * 64 + w * 16 + l16) * DH + quad * 8;
  short8 qa0 = *(const short8*)(qp);
  short8 qa1 = *(const short8*)(qp + 32);

  const unsigned short* kbase = kb + (size_t)bh * SP * DH;
  const unsigned short* vbase = vt + (size_t)bh * DH * SP;

  floatx4 o[4];
#pragma unroll
  for (int i = 0; i < 4; i++) {
    floatx4 z = {0.f, 0.f, 0.f, 0.f};
    o[i] = z;
  }
  float mrow[4] = {-1e30f, -1e30f, -1e30f, -1e30f};
  float lrow[4] = {0.f, 0.f, 0.f, 0.f};

  for (int s0 = 0; s0 < SP; s0 += 128) {
    __syncthreads();  // previous iter's LDS reads complete
    {
      const int4* src = (const int4*)(kbase + (size_t)s0 * DH);
      for (int i = t; i < 128 * DH / 8; i += 256) {
        int row = i >> 3, c = i & 7;
        *(int4*)&Ks[row * 72 + c * 8] = src[i];
      }
      for (int i = t; i < 64 * 128 / 8; i += 256) {
        int d = i >> 4, c = i & 15;
        *(int4*)&Vs[d * 136 + c * 8] = *(const int4*)(vbase + (size_t)d * SP + s0 + c * 8);
      }
    }
    __syncthreads();

    // scores: 16 rows x 128 cols per wave
    floatx4 sc[8];
#pragma unroll
    for (int nb = 0; nb < 8; nb++) {
      short8 k0 = *(const short8*)&Ks[(nb * 16 + l16) * 72 + quad * 8];
      short8 k1 = *(const short8*)&Ks[(nb * 16 + l16) * 72 + 32 + quad * 8];
      floatx4 a = {0.f, 0.f, 0.f, 0.f};
      a = mfma16(qa0, k0, a);
      a = mfma16(qa1, k1, a);
      int sg = s0 + nb * 16 + l16;
      if (sg >= S_) {
        floatx4 neg = {-1e30f, -1e30f, -1e30f, -1e30f};
        a = neg;
      }
      sc[nb] = a;
    }

    // online softmax (rows live across the 16-lane group)
    float alpha[4];
#pragma unroll
    for (int r = 0; r < 4; r++) {
      float mx = sc[0][r];
#pragma unroll
      for (int nb = 1; nb < 8; nb++) mx = fmaxf(mx, sc[nb][r]);
      for (int off = 1; off < 16; off <<= 1) mx = fmaxf(mx, __shfl_xor(mx, off));
      float mnew = fmaxf(mrow[r], mx);
      alpha[r] = __expf(mrow[r] - mnew);
      mrow[r] = mnew;
      float rs = 0.f;
#pragma unroll
      for (int nb = 0; nb < 8; nb++) {
        float p = __expf(sc[nb][r] - mnew);
        sc[nb][r] = p;
        rs += p;
      }
      for (int off = 1; off < 16; off <<= 1) rs += __shfl_xor(rs, off);
      lrow[r] = lrow[r] * alpha[r] + rs;
    }
#pragma unroll
    for (int nb2 = 0; nb2 < 4; nb2++) {
      o[nb2][0] *= alpha[0];
      o[nb2][1] *= alpha[1];
      o[nb2][2] *= alpha[2];
      o[nb2][3] *= alpha[3];
    }

    // P (C-layout) -> LDS -> A-layout
    int pr = w * 16 + quad * 4;
#pragma unroll
    for (int nb = 0; nb < 8; nb++)
#pragma unroll
      for (int r = 0; r < 4; r++)
        Ps[(pr + r) * 136 + nb * 16 + l16] = f2bf(sc[nb][r]);
    __syncthreads();

    int prow = w * 16 + l16;
#pragma unroll
    for (int kf = 0; kf < 4; kf++) {
      short8 pf = *(const short8*)&Ps[prow * 136 + kf * 32 + quad * 8];
#pragma unroll
      for (int nb2 = 0; nb2 < 4; nb2++) {
        short8 vf = *(const short8*)&Vs[(nb2 * 16 + l16) * 136 + kf * 32 + quad * 8];
        o[nb2] = mfma16(pf, vf, o[nb2]);
      }
    }
  }

  float inv[4];
#pragma unroll
  for (int r = 0; r < 4; r++) inv[r] = 1.0f / lrow[r];
  int trow = ttile * 64 + w * 16 + quad * 4;
#pragma unroll
  for (int nb2 = 0; nb2 < 4; nb2++) {
    int dh = nb2 * 16 + l16;
#pragma unroll
    for (int r = 0; r < 4; r++) {
      ob[((size_t)(b * T_ + trow + r) * H_ + h) * DH + dh] = f2bf(o[nb2][r] * inv[r]);
    }
  }
}

extern "C" void kernel_launch(void* const* d_in, const int* in_sizes, int n_in,
                              void* d_out, int out_size, void* d_ws, size_t ws_size,
                              hipStream_t stream) {
  const float* x  = (const float*)d_in[0];
  const float* k  = (const float*)d_in[1];
  const float* v  = (const float*)d_in[2];
  const float* wq = (const float*)d_in[3];
  const float* bq = (const float*)d_in[4];
  const float* wo = (const float*)d_in[5];
  const float* bo = (const float*)d_in[6];
  float* out = (float*)d_out;

  char* ws = (char*)d_ws;
  unsigned short* xb  = (unsigned short*)(ws + 0);           // 16,777,216 B
  unsigned short* wqb = (unsigned short*)(ws + 16777216);    //  2,097,152 B
  unsigned short* wob = (unsigned short*)(ws + 18874368);    //  2,097,152 B
  unsigned short* kbp = (unsigned short*)(ws + 20971520);    // 25,165,824 B
  unsigned short* vtp = (unsigned short*)(ws + 46137344);    // 25,165,824 B
  unsigned short* qsp = (unsigned short*)(ws + 71303168);    // 16,777,216 B
  unsigned short* obp = (unsigned short*)(ws + 88080384);    // 16,777,216 B
  // total 104,857,600 B

  // 1. casts
  {
    int n4 = B_ * T_ * D_ / 4;  // 2,097,152
    cast_bf16_kernel<<<n4 / 256, 256, 0, stream>>>(x, xb, n4);
  }
  {
    int n4 = D_ * D_ / 4;  // 262,144
    cast_bf16_kernel<<<n4 / 256, 256, 0, stream>>>(wq, wqb, n4);
    cast_bf16_kernel<<<n4 / 256, 256, 0, stream>>>(wo, wob, n4);
  }
  // 2. pack K / transpose V
  {
    int groups = B_ * H_ * SP * 16;  // 3,145,728
    pack_k_kernel<<<groups / 256, 256, 0, stream>>>(k, kbp);
    pack_vt_kernel<<<dim3(SP / 64, B_ * H_), 256, 0, stream>>>(v, vtp);
  }
  // 3. q projection -> qs [B,H,T,DH] bf16 (pre-scaled)
  gemm_bt<<<dim3(D_ / 128, B_ * T_ / 128), 256, 0, stream>>>(xb, wqb, bq, qsp, 0);
  // 4. attention -> ob [B,T,H,DH] bf16
  attn_kernel<<<dim3(T_ / 64, B_ * H_), 256, 0, stream>>>(qsp, kbp, vtp, obp);
  // 5. out projection -> fp32 out
  gemm_bt<<<dim3(D_ / 128, B_ * T_ / 128), 256, 0, stream>>>(obp, wob, bo, out, 1);
}

// Round 2
// 358.232 us; speedup vs baseline: 1.1858x; 1.1858x over previous
//
#include <hip/hip_runtime.h>

typedef __attribute__((ext_vector_type(8))) short short8;
typedef __attribute__((ext_vector_type(4))) float floatx4;

#define B_ 8
#define T_ 1024
#define S_ 1500
#define SP 1536
#define D_ 1024
#define H_ 16
#define DH 64
#define SCALE_ 0.125f

__device__ __forceinline__ unsigned short f2bf(float f) {
  unsigned u = __float_as_uint(f);
  u += 0x7fffu + ((u >> 16) & 1u);
  return (unsigned short)(u >> 16);
}

__device__ __forceinline__ floatx4 mfma16(short8 a, short8 b, floatx4 c) {
  return __builtin_amdgcn_mfma_f32_16x16x32_bf16(a, b, c, 0, 0, 0);
}

// ---------------- prep: fp32 -> bf16 cast (vectorized) ----------------
__global__ void cast_bf16_kernel(const float* __restrict__ src,
                                 unsigned short* __restrict__ dst, int n4) {
  int i = blockIdx.x * blockDim.x + threadIdx.x;
  if (i < n4) {
    float4 v = ((const float4*)src)[i];
    ushort4 o;
    o.x = f2bf(v.x); o.y = f2bf(v.y); o.z = f2bf(v.z); o.w = f2bf(v.w);
    ((ushort4*)dst)[i] = o;
  }
}

// ---------------- prep: K [B,S,H,DH] f32 -> [B,H,SP,DH] bf16, ROW-PERMUTED ------
// staged position p (within each 32-block) holds actual s-offset q*8+half*4+r
// where q=(p>>2)&3, half=(p>>4)&1, r=p&3. Zero-pad actual s >= S_.
__global__ void pack_k_kernel(const float* __restrict__ k,
                              unsigned short* __restrict__ kb) {
  int i = blockIdx.x * blockDim.x + threadIdx.x;  // group of 4 dh
  int dh4 = (i & 15) * 4;
  int j = i >> 4;
  int s = j % SP;   // staged position
  int bh = j / SP;
  if (bh >= B_ * H_) return;
  int b = bh >> 4, h = bh & 15;
  int p = s & 31;
  int src = (s & ~31) + ((p >> 2) & 3) * 8 + ((p >> 4) & 1) * 4 + (p & 3);
  ushort4 o;
  if (src < S_) {
    float4 v = *(const float4*)(k + (((size_t)(b * S_ + src) * H_ + h) * DH) + dh4);
    o.x = f2bf(v.x); o.y = f2bf(v.y); o.z = f2bf(v.z); o.w = f2bf(v.w);
  } else {
    o = make_ushort4(0, 0, 0, 0);
  }
  *(ushort4*)(kb + ((size_t)bh * SP + s) * DH + dh4) = o;
}

// ---------------- prep: V [B,S,H,DH] f32 -> transposed [B,H,DH,SP] bf16 (plain) -
__global__ void pack_vt_kernel(const float* __restrict__ v,
                               unsigned short* __restrict__ vt) {
  __shared__ unsigned short tile[64][72];  // [dh][s], padded
  int st = blockIdx.x, bh = blockIdx.y;
  int b = bh >> 4, h = bh & 15;
  int s0 = st * 64;
  int t = threadIdx.x;
  for (int i = t; i < 1024; i += 256) {
    int sl = i >> 4, dh4 = (i & 15) * 4;
    float4 val = make_float4(0.f, 0.f, 0.f, 0.f);
    if (s0 + sl < S_)
      val = *(const float4*)(v + ((size_t)((b * S_ + s0 + sl) * H_ + h)) * DH + dh4);
    tile[dh4 + 0][sl] = f2bf(val.x);
    tile[dh4 + 1][sl] = f2bf(val.y);
    tile[dh4 + 2][sl] = f2bf(val.z);
    tile[dh4 + 3][sl] = f2bf(val.w);
  }
  __syncthreads();
  for (int i = t; i < 1024; i += 256) {
    int d = i >> 4, s4 = (i & 15) * 4;
    ushort4 o;
    o.x = tile[d][s4]; o.y = tile[d][s4 + 1]; o.z = tile[d][s4 + 2]; o.w = tile[d][s4 + 3];
    *(ushort4*)(vt + ((size_t)bh * DH + d) * SP + s0 + s4) = o;
  }
}

// ---------------- bf16 GEMM  C[m,n] = sum_k A[m,k]*B[n,k]  (+bias epilogues) -----
#define BK 32
#define ASTR 40
__global__ __launch_bounds__(256) void gemm_bt(const unsigned short* __restrict__ A,
                                               const unsigned short* __restrict__ Bm,
                                               const float* __restrict__ bias,
                                               void* __restrict__ outp, int epi) {
  __shared__ unsigned short As[128 * ASTR];
  __shared__ unsigned short Bs[128 * ASTR];
  const int K = 1024;
  int t = threadIdx.x;
  int m0 = blockIdx.y * 128, n0 = blockIdx.x * 128;
  int w = t >> 6, lane = t & 63, quad = lane >> 4, l16 = lane & 15;
  int mw = (w & 1) * 64, nw = (w >> 1) * 64;
  int lrow = t >> 2, lcol = (t & 3) * 8;

  const unsigned short* Ag = A + (size_t)(m0 + lrow) * K + lcol;
  const unsigned short* Bg = Bm + (size_t)(n0 + lrow) * K + lcol;

  floatx4 acc[4][4];
#pragma unroll
  for (int i = 0; i < 4; i++)
#pragma unroll
    for (int j = 0; j < 4; j++) {
      floatx4 z = {0.f, 0.f, 0.f, 0.f};
      acc[i][j] = z;
    }

  int4 a0 = *(const int4*)(Ag);
  int4 a1 = *(const int4*)(Ag + (size_t)64 * K);
  int4 b0 = *(const int4*)(Bg);
  int4 b1 = *(const int4*)(Bg + (size_t)64 * K);

  for (int kt = 0; kt < K / BK; kt++) {
    __syncthreads();
    *(int4*)&As[lrow * ASTR + lcol] = a0;
    *(int4*)&As[(lrow + 64) * ASTR + lcol] = a1;
    *(int4*)&Bs[lrow * ASTR + lcol] = b0;
    *(int4*)&Bs[(lrow + 64) * ASTR + lcol] = b1;
    __syncthreads();
    if (kt + 1 < K / BK) {
      a0 = *(const int4*)(Ag + (kt + 1) * BK);
      a1 = *(const int4*)(Ag + (size_t)64 * K + (kt + 1) * BK);
      b0 = *(const int4*)(Bg + (kt + 1) * BK);
      b1 = *(const int4*)(Bg + (size_t)64 * K + (kt + 1) * BK);
    }
    short8 af[4], bf[4];
#pragma unroll
    for (int mi = 0; mi < 4; mi++)
      af[mi] = *(const short8*)&As[(mw + mi * 16 + l16) * ASTR + quad * 8];
#pragma unroll
    for (int ni = 0; ni < 4; ni++)
      bf[ni] = *(const short8*)&Bs[(nw + ni * 16 + l16) * ASTR + quad * 8];
#pragma unroll
    for (int mi = 0; mi < 4; mi++)
#pragma unroll
      for (int ni = 0; ni < 4; ni++)
        acc[mi][ni] = mfma16(af[mi], bf[ni], acc[mi][ni]);
  }

#pragma unroll
  for (int mi = 0; mi < 4; mi++)
#pragma unroll
    for (int ni = 0; ni < 4; ni++) {
      int row = m0 + mw + mi * 16 + quad * 4;
      int col = n0 + nw + ni * 16 + l16;
      float bcol = bias[col];
#pragma unroll
      for (int r = 0; r < 4; r++) {
        float val = acc[mi][ni][r] + bcol;
        int rr = row + r;
        if (epi == 0) {
          int b = rr >> 10, tt = rr & 1023, h = col >> 6, dh = col & 63;
          ((unsigned short*)outp)[(((size_t)(b * 16 + h) * 1024) + tt) * 64 + dh] =
              f2bf(val * SCALE_);
        } else {
          ((float*)outp)[(size_t)rr * 1024 + col] = val;
        }
      }
    }
}

// ---------------- fused flash attention, Sc^T scheme -------------------------
// grid (T/64, B*H), block 256 (4 waves); wave owns 16 t-columns (t = w*16+l16).
// Scores computed transposed: C col = t (lane), row = staged s (quad*4+reg).
// K staged row-permuted so P fragments re-pack in-lane as PV B-operand.
__global__ __launch_bounds__(256, 4) void attn_kernel(
    const unsigned short* __restrict__ qs, const unsigned short* __restrict__ kb,
    const unsigned short* __restrict__ vt, unsigned short* __restrict__ ob) {
  __shared__ unsigned short Ks[128 * 72];   // [staged s][dh] padded
  __shared__ unsigned short Vs[64 * 136];   // [dh][s] padded (plain order)
  int ttile = blockIdx.x, bh = blockIdx.y;
  int b = bh >> 4, h = bh & 15;
  int t = threadIdx.x, w = t >> 6, lane = t & 63, quad = lane >> 4, l16 = lane & 15;

  // Q as B-operand: n = t = l16, k(dh) = quad*8 + j
  const unsigned short* qp =
      qs + ((size_t)bh * T_ + ttile * 64 + w * 16 + l16) * DH + quad * 8;
  short8 qa0 = *(const short8*)(qp);
  short8 qa1 = *(const short8*)(qp + 32);

  const unsigned short* kbase = kb + (size_t)bh * SP * DH;
  const unsigned short* vbase = vt + (size_t)bh * DH * SP;

  floatx4 o[4];  // O^T acc: col=t(l16), row = db*16 + quad*4 + r (= dh)
#pragma unroll
  for (int i = 0; i < 4; i++) {
    floatx4 z = {0.f, 0.f, 0.f, 0.f};
    o[i] = z;
  }
  float mrow = -1e30f, lrow = 0.f;  // per-lane: this lane's t-row state

  for (int s0 = 0; s0 < SP; s0 += 128) {
    __syncthreads();
    {
      const int4* src = (const int4*)(kbase + (size_t)s0 * DH);
      for (int i = t; i < 128 * DH / 8; i += 256) {
        int row = i >> 3, c = i & 7;
        *(int4*)&Ks[row * 72 + c * 8] = src[i];
      }
      for (int i = t; i < 64 * 128 / 8; i += 256) {
        int d = i >> 4, c = i & 15;
        *(int4*)&Vs[d * 136 + c * 8] = *(const int4*)(vbase + (size_t)d * SP + s0 + c * 8);
      }
    }
    __syncthreads();

    // Sc^T: per lane 32 staged-s values of its own t-row
    floatx4 sc[8];
#pragma unroll
    for (int nb = 0; nb < 8; nb++) {
      short8 k0 = *(const short8*)&Ks[(nb * 16 + l16) * 72 + quad * 8];
      short8 k1 = *(const short8*)&Ks[(nb * 16 + l16) * 72 + 32 + quad * 8];
      floatx4 a = {0.f, 0.f, 0.f, 0.f};
      a = mfma16(k0, qa0, a);
      a = mfma16(k1, qa1, a);
      sc[nb] = a;
    }
    if (s0 + 128 > S_) {  // mask padded actual-s (last tile only)
#pragma unroll
      for (int nb = 0; nb < 8; nb++)
#pragma unroll
        for (int r = 0; r < 4; r++) {
          int s_act = s0 + (nb >> 1) * 32 + quad * 8 + (nb & 1) * 4 + r;
          if (s_act >= S_) sc[nb][r] = -1e30f;
        }
    }

    // online softmax: in-lane over 32 + 2 shfl across quads
    float mx = -1e30f;
#pragma unroll
    for (int nb = 0; nb < 8; nb++) {
      float a0m = fmaxf(sc[nb][0], sc[nb][1]);
      float a1m = fmaxf(sc[nb][2], sc[nb][3]);
      mx = fmaxf(mx, fmaxf(a0m, a1m));
    }
    mx = fmaxf(mx, __shfl_xor(mx, 16));
    mx = fmaxf(mx, __shfl_xor(mx, 32));
    float mnew = fmaxf(mrow, mx);
    float alpha = __expf(mrow - mnew);
    mrow = mnew;
    float rs = 0.f;
#pragma unroll
    for (int nb = 0; nb < 8; nb++) {
#pragma unroll
      for (int r = 0; r < 4; r++) {
        float p = __expf(sc[nb][r] - mnew);
        sc[nb][r] = p;
        rs += p;
      }
    }
    rs += __shfl_xor(rs, 16);
    rs += __shfl_xor(rs, 32);
    lrow = lrow * alpha + rs;
#pragma unroll
    for (int db = 0; db < 4; db++) {
      o[db][0] *= alpha; o[db][1] *= alpha; o[db][2] *= alpha; o[db][3] *= alpha;
    }

    // PV: O^T[d][t] += V^T(A) * P(B).  chunk c covers staged s = c*32..c*32+31
#pragma unroll
    for (int c = 0; c < 4; c++) {
      union { short8 v; unsigned short u[8]; } pk;
#pragma unroll
      for (int r = 0; r < 4; r++) {
        pk.u[r] = f2bf(sc[2 * c][r]);
        pk.u[4 + r] = f2bf(sc[2 * c + 1][r]);
      }
#pragma unroll
      for (int db = 0; db < 4; db++) {
        short8 vf = *(const short8*)&Vs[(db * 16 + l16) * 136 + c * 32 + quad * 8];
        o[db] = mfma16(vf, pk.v, o[db]);
      }
    }
  }

  float inv = 1.0f / lrow;
  int tg = ttile * 64 + w * 16 + l16;
#pragma unroll
  for (int db = 0; db < 4; db++) {
    int dh = db * 16 + quad * 4;
    ushort4 st;
    st.x = f2bf(o[db][0] * inv);
    st.y = f2bf(o[db][1] * inv);
    st.z = f2bf(o[db][2] * inv);
    st.w = f2bf(o[db][3] * inv);
    *(ushort4*)(ob + ((size_t)(b * T_ + tg) * H_ + h) * DH + dh) = st;
  }
}

extern "C" void kernel_launch(void* const* d_in, const int* in_sizes, int n_in,
                              void* d_out, int out_size, void* d_ws, size_t ws_size,
                              hipStream_t stream) {
  const float* x  = (const float*)d_in[0];
  const float* k  = (const float*)d_in[1];
  const float* v  = (const float*)d_in[2];
  const float* wq = (const float*)d_in[3];
  const float* bq = (const float*)d_in[4];
  const float* wo = (const float*)d_in[5];
  const float* bo = (const float*)d_in[6];
  float* out = (float*)d_out;

  char* ws = (char*)d_ws;
  unsigned short* xb  = (unsigned short*)(ws + 0);
  unsigned short* wqb = (unsigned short*)(ws + 16777216);
  unsigned short* wob = (unsigned short*)(ws + 18874368);
  unsigned short* kbp = (unsigned short*)(ws + 20971520);
  unsigned short* vtp = (unsigned short*)(ws + 46137344);
  unsigned short* qsp = (unsigned short*)(ws + 71303168);
  unsigned short* obp = (unsigned short*)(ws + 88080384);

  {
    int n4 = B_ * T_ * D_ / 4;
    cast_bf16_kernel<<<n4 / 256, 256, 0, stream>>>(x, xb, n4);
  }
  {
    int n4 = D_ * D_ / 4;
    cast_bf16_kernel<<<n4 / 256, 256, 0, stream>>>(wq, wqb, n4);
    cast_bf16_kernel<<<n4 / 256, 256, 0, stream>>>(wo, wob, n4);
  }
  {
    int groups = B_ * H_ * SP * 16;
    pack_k_kernel<<<groups / 256, 256, 0, stream>>>(k, kbp);
    pack_vt_kernel<<<dim3(SP / 64, B_ * H_), 256, 0, stream>>>(v, vtp);
  }
  gemm_bt<<<dim3(D_ / 128, B_ * T_ / 128), 256, 0, stream>>>(xb, wqb, bq, qsp, 0);
  attn_kernel<<<dim3(T_ / 64, B_ * H_), 256, 0, stream>>>(qsp, kbp, vtp, obp);
  gemm_bt<<<dim3(D_ / 128, B_ * T_ / 128), 256, 0, stream>>>(obp, wob, bo, out, 1);
}